// Round 1
// baseline (742.510 us; speedup 1.0000x reference)
//
#include <hip/hip_runtime.h>

typedef unsigned short u16;
typedef __attribute__((ext_vector_type(8))) short s16x8;
typedef __attribute__((ext_vector_type(4))) float f32x4;

__device__ __forceinline__ u16 f2bf(float f) {
  unsigned u = __float_as_uint(f);
  u += 0x7fffu + ((u >> 16) & 1u);   // RNE
  return (u16)(u >> 16);
}
__device__ __forceinline__ float bf2f(u16 h) {
  return __uint_as_float(((unsigned)h) << 16);
}

typedef __attribute__((address_space(1))) const void gvoid_t;
typedef __attribute__((address_space(3))) void lvoid_t;
__device__ __forceinline__ void gload_lds16(const void* g, void* l) {
  __builtin_amdgcn_global_load_lds((gvoid_t*)g, (lvoid_t*)l, 16, 0, 0);
}

// ---------------- f32 -> bf16 convert (vectorized) ----------------
__global__ void cvt_f32_bf16(const float* __restrict__ in, u16* __restrict__ out, int n) {
  int i = (blockIdx.x * 256 + threadIdx.x) * 4;
  if (i >= n) return;
  float4 v = *(const float4*)(in + i);
  ushort4 o;
  o.x = f2bf(v.x); o.y = f2bf(v.y); o.z = f2bf(v.z); o.w = f2bf(v.w);
  *(ushort4*)(out + i) = o;
}

// ---------------- GEMM: C[M,N] = A[M,K] * B[N,K]^T  (m97 structure) ----------------
// 128x128 tile, BK=64, 256 threads = 4 waves (2x2), 16x16x32 bf16 MFMA.
template<typename OutT, bool BIAS>
__global__ __launch_bounds__(256) void gemm_bt(
    const u16* __restrict__ A, const u16* __restrict__ Bm,
    OutT* __restrict__ C, const float* __restrict__ bias,
    int M, int N, int K)
{
  __shared__ u16 As[128 * 64];
  __shared__ u16 Bs[128 * 64];

  const int t = threadIdx.x;
  const int lane = t & 63, wid = t >> 6;
  const int wm = wid >> 1, wn = wid & 1;
  const int lr = lane & 15, lk = lane >> 4;
  const int m0 = blockIdx.y * 128, n0 = blockIdx.x * 128;

  f32x4 acc[4][4] = {};

  for (int k0 = 0; k0 < K; k0 += 64) {
    // stage A,B tiles: 128 rows x 64 cols bf16 each, 16B chunks, linear LDS
#pragma unroll
    for (int it = 0; it < 4; ++it) {
      int id = it * 256 + t;
      int r = id >> 3, c8 = (id & 7) << 3;
      gload_lds16(A + (size_t)(m0 + r) * K + k0 + c8, &As[id * 8]);
      gload_lds16(Bm + (size_t)(n0 + r) * K + k0 + c8, &Bs[id * 8]);
    }
    __syncthreads();

#pragma unroll
    for (int kk = 0; kk < 2; ++kk) {
      s16x8 af[4], bf[4];
#pragma unroll
      for (int i = 0; i < 4; ++i) {
        af[i] = *(const s16x8*)&As[(wm * 64 + i * 16 + lr) * 64 + kk * 32 + lk * 8];
        bf[i] = *(const s16x8*)&Bs[(wn * 64 + i * 16 + lr) * 64 + kk * 32 + lk * 8];
      }
#pragma unroll
      for (int i = 0; i < 4; ++i)
#pragma unroll
        for (int j = 0; j < 4; ++j)
          acc[i][j] = __builtin_amdgcn_mfma_f32_16x16x32_bf16(af[i], bf[j], acc[i][j], 0, 0, 0);
    }
    __syncthreads();
  }

  // epilogue: D layout col=lane&15, row=(lane>>4)*4+reg  [m89/m91]
#pragma unroll
  for (int i = 0; i < 4; ++i) {
    int row_b = m0 + wm * 64 + i * 16 + lk * 4;
#pragma unroll
    for (int j = 0; j < 4; ++j) {
      int col = n0 + wn * 64 + j * 16 + lr;
      float bv = BIAS ? bias[col] : 0.f;
#pragma unroll
      for (int r = 0; r < 4; ++r) {
        float v = acc[i][j][r] + bv;
        size_t off = (size_t)(row_b + r) * N + col;
        if constexpr (sizeof(OutT) == 2) ((u16*)C)[off] = f2bf(v);
        else                             ((float*)C)[off] = v;
      }
    }
  }
}

// ---------------- RoPE on Q and K in place (bf16) ----------------
__global__ void rope_qk(u16* __restrict__ Q, u16* __restrict__ Kt,
                        const float* __restrict__ cosp, const float* __restrict__ sinp) {
  int i = blockIdx.x * 256 + threadIdx.x;   // over S*H*64
  int d = i & 63;
  int h = (i >> 6) & 31;
  int s = i >> 11;
  float c = cosp[s * 128 + d], sn = sinp[s * 128 + d];
  size_t base = (size_t)s * 4096 + h * 128 + d;
  float q1 = bf2f(Q[base]), q2 = bf2f(Q[base + 64]);
  Q[base]      = f2bf(q1 * c - q2 * sn);
  Q[base + 64] = f2bf(q2 * c + q1 * sn);
  float k1 = bf2f(Kt[base]), k2 = bf2f(Kt[base + 64]);
  Kt[base]      = f2bf(k1 * c - k2 * sn);
  Kt[base + 64] = f2bf(k2 * c + k1 * sn);
}

// ---------------- Flash attention (causal), 4 waves x 16 q-rows, KVBLK=32 ----------------
__global__ __launch_bounds__(256) void flash_attn(
    const u16* __restrict__ Q, const u16* __restrict__ Kg, const u16* __restrict__ Vg,
    u16* __restrict__ Ctx)
{
  const int D = 4096;
  __shared__ u16 Ks[32 * 128];    // [kv][d], swizzled 16B-chunks (src pre-swizzle)
  __shared__ u16 Vt[128 * 32];    // [d][kv], kv-block XOR swizzle
  __shared__ u16 Ps[4][16 * 32];  // per-wave P exchange

  const int t = threadIdx.x, lane = t & 63, wid = t >> 6;
  const int lr = lane & 15, lk = lane >> 4;
  const int h = blockIdx.y;
  const int q0 = blockIdx.x * 64;

  // Q fragment in registers: A-frag row = lane&15
  const int qrow = q0 + wid * 16 + lr;
  s16x8 qf[4];
#pragma unroll
  for (int kc = 0; kc < 4; ++kc)
    qf[kc] = *(const s16x8*)(Q + (size_t)qrow * D + h * 128 + kc * 32 + lk * 8);

  f32x4 o[8] = {};
  float m_r[4] = {-INFINITY, -INFINITY, -INFINITY, -INFINITY};
  float l_r[4] = {0.f, 0.f, 0.f, 0.f};

  const int ntiles = q0 / 32 + 2;
  const float scale = 0.08838834764831845f;  // 1/sqrt(128)

  for (int kt = 0; kt < ntiles; ++kt) {
    const int kv0 = kt * 32;
    // K tile via global_load_lds, source pre-swizzled: chunk ch0 <- global chunk ch0^(kv&7)
#pragma unroll
    for (int it = 0; it < 2; ++it) {
      int id = it * 256 + t;
      int kv = id >> 4, ch0 = id & 15;
      int chs = ch0 ^ (kv & 7);
      gload_lds16(Kg + (size_t)(kv0 + kv) * D + h * 128 + chs * 8, &Ks[id * 8]);
    }
    // V tile transposed into Vt[d][kv], kv-block swizzle: kv' = kv ^ (((d>>3)&3)<<3)
#pragma unroll
    for (int it = 0; it < 2; ++it) {
      int id = it * 256 + t;
      int kv = id >> 4, c8 = (id & 15) << 3;
      s16x8 vv = *(const s16x8*)(Vg + (size_t)(kv0 + kv) * D + h * 128 + c8);
#pragma unroll
      for (int j = 0; j < 8; ++j) {
        int c = c8 + j;
        Vt[c * 32 + (kv ^ (((c >> 3) & 3) << 3))] = (u16)vv[j];
      }
    }
    __syncthreads();

    // QK^T: S_tile(16x32) ; B-frag row = kv (lane&15), swizzled chunk read
    f32x4 st[2] = {};
#pragma unroll
    for (int nt = 0; nt < 2; ++nt) {
      int r = nt * 16 + lr;
#pragma unroll
      for (int kc = 0; kc < 4; ++kc) {
        int ch = kc * 4 + lk;
        s16x8 kf = *(const s16x8*)&Ks[r * 128 + (ch ^ (r & 7)) * 8];
        st[nt] = __builtin_amdgcn_mfma_f32_16x16x32_bf16(qf[kc], kf, st[nt], 0, 0, 0);
      }
    }

    // online softmax (rows live in 16-lane groups; reduce via shfl_xor 1,2,4,8)
    float p[2][4];
#pragma unroll
    for (int r = 0; r < 4; ++r) {
      int q_r = q0 + wid * 16 + lk * 4 + r;
      float s0 = (kv0 + lr      <= q_r) ? st[0][r] * scale : -INFINITY;
      float s1 = (kv0 + 16 + lr <= q_r) ? st[1][r] * scale : -INFINITY;
      float vmax = fmaxf(s0, s1);
#pragma unroll
      for (int off = 1; off < 16; off <<= 1)
        vmax = fmaxf(vmax, __shfl_xor(vmax, off));
      float mn = fmaxf(m_r[r], vmax);
      float p0 = __expf(s0 - mn);
      float p1 = __expf(s1 - mn);
      float ps = p0 + p1;
#pragma unroll
      for (int off = 1; off < 16; off <<= 1)
        ps += __shfl_xor(ps, off);
      float alpha = __expf(m_r[r] - mn);
      l_r[r] = l_r[r] * alpha + ps;
      m_r[r] = mn;
      p[0][r] = p0; p[1][r] = p1;
#pragma unroll
      for (int nb = 0; nb < 8; ++nb) o[nb][r] *= alpha;
    }

    // P: D-layout -> A-layout via per-wave LDS roundtrip
#pragma unroll
    for (int nt = 0; nt < 2; ++nt)
#pragma unroll
      for (int r = 0; r < 4; ++r)
        Ps[wid][(lk * 4 + r) * 32 + nt * 16 + lr] = f2bf(p[nt][r]);
    asm volatile("s_waitcnt lgkmcnt(0)" ::: "memory");
    s16x8 pa = *(const s16x8*)&Ps[wid][lr * 32 + lk * 8];

    // PV: O(16x128) += P(16x32) * V(32x128); B-frag col = d (lane&15), k = kv
#pragma unroll
    for (int nb = 0; nb < 8; ++nb) {
      int c = nb * 16 + lr;
      s16x8 vf = *(const s16x8*)&Vt[c * 32 + ((lk ^ ((c >> 3) & 3)) << 3)];
      o[nb] = __builtin_amdgcn_mfma_f32_16x16x32_bf16(pa, vf, o[nb], 0, 0, 0);
    }
    __syncthreads();
  }

  // normalize + write ctx (bf16)
#pragma unroll
  for (int nb = 0; nb < 8; ++nb) {
#pragma unroll
    for (int r = 0; r < 4; ++r) {
      int q_r = q0 + wid * 16 + lk * 4 + r;
      Ctx[(size_t)q_r * D + h * 128 + nb * 16 + lr] = f2bf(o[nb][r] / l_r[r]);
    }
  }
}

// ---------------- launcher ----------------
extern "C" void kernel_launch(void* const* d_in, const int* in_sizes, int n_in,
                              void* d_out, int out_size, void* d_ws, size_t ws_size,
                              hipStream_t stream) {
  const int S = 2048, D = 4096, H = 32;
  const size_t SD = (size_t)S * D, DD = (size_t)D * D;

  const float* X  = (const float*)d_in[0];
  const float* Wq = (const float*)d_in[1];
  const float* Wk = (const float*)d_in[2];
  const float* Wv = (const float*)d_in[3];
  const float* Wo = (const float*)d_in[4];
  const float* bo = (const float*)d_in[5];
  const float* cs = (const float*)d_in[6];
  const float* sn = (const float*)d_in[7];

  // ws layout (bf16): WB[DD] (weight, reused 4x) | Xb[SD] (X, later Ctx) | Qb | Kb | Vb
  // total = 2*(DD + 4*SD) = 96 MiB
  u16* WB = (u16*)d_ws;
  u16* Xb = WB + DD;
  u16* Qb = Xb + SD;
  u16* Kb = Qb + SD;
  u16* Vb = Kb + SD;

  dim3 blk(256);
  dim3 gg(D / 128, S / 128);

  cvt_f32_bf16<<<(int)(SD / 1024), blk, 0, stream>>>(X, Xb, (int)SD);
  cvt_f32_bf16<<<(int)(DD / 1024), blk, 0, stream>>>(Wq, WB, (int)DD);
  gemm_bt<u16, false><<<gg, blk, 0, stream>>>(Xb, WB, Qb, nullptr, S, D, D);
  cvt_f32_bf16<<<(int)(DD / 1024), blk, 0, stream>>>(Wk, WB, (int)DD);
  gemm_bt<u16, false><<<gg, blk, 0, stream>>>(Xb, WB, Kb, nullptr, S, D, D);
  cvt_f32_bf16<<<(int)(DD / 1024), blk, 0, stream>>>(Wv, WB, (int)DD);
  gemm_bt<u16, false><<<gg, blk, 0, stream>>>(Xb, WB, Vb, nullptr, S, D, D);

  rope_qk<<<(S * H * 64) / 256, blk, 0, stream>>>(Qb, Kb, cs, sn);

  flash_attn<<<dim3(S / 64, H), blk, 0, stream>>>(Qb, Kb, Vb, Xb /*Ctx*/);

  cvt_f32_bf16<<<(int)(DD / 1024), blk, 0, stream>>>(Wo, WB, (int)DD);
  gemm_bt<float, true><<<gg, blk, 0, stream>>>(Xb, WB, (float*)d_out, bo, S, D, D);
}

// Round 2
// 646.332 us; speedup vs baseline: 1.1488x; 1.1488x over previous
//
#include <hip/hip_runtime.h>

typedef unsigned short u16;
typedef __attribute__((ext_vector_type(8))) short s16x8;
typedef __attribute__((ext_vector_type(4))) float f32x4;

__device__ __forceinline__ u16 f2bf(float f) {
  unsigned u = __float_as_uint(f);
  u += 0x7fffu + ((u >> 16) & 1u);   // RNE
  return (u16)(u >> 16);
}
__device__ __forceinline__ float bf2f(u16 h) {
  return __uint_as_float(((unsigned)h) << 16);
}

typedef __attribute__((address_space(1))) const void gvoid_t;
typedef __attribute__((address_space(3))) void lvoid_t;
__device__ __forceinline__ void gload_lds16(const void* g, void* l) {
  __builtin_amdgcn_global_load_lds((gvoid_t*)g, (lvoid_t*)l, 16, 0, 0);
}

// ---------------- f32 -> bf16 convert (vectorized) ----------------
__global__ void cvt_f32_bf16(const float* __restrict__ in, u16* __restrict__ out, int n) {
  int i = (blockIdx.x * 256 + threadIdx.x) * 4;
  if (i >= n) return;
  float4 v = *(const float4*)(in + i);
  ushort4 o;
  o.x = f2bf(v.x); o.y = f2bf(v.y); o.z = f2bf(v.z); o.w = f2bf(v.w);
  *(ushort4*)(out + i) = o;
}

// ---------------- GEMM: C[M,N] = A[M,K] * B[N,K]^T  (m97 structure) ----------------
template<typename OutT, bool BIAS>
__global__ __launch_bounds__(256) void gemm_bt(
    const u16* __restrict__ A, const u16* __restrict__ Bm,
    OutT* __restrict__ C, const float* __restrict__ bias,
    int M, int N, int K)
{
  __shared__ u16 As[128 * 64];
  __shared__ u16 Bs[128 * 64];

  const int t = threadIdx.x;
  const int lane = t & 63, wid = t >> 6;
  const int wm = wid >> 1, wn = wid & 1;
  const int lr = lane & 15, lk = lane >> 4;
  const int m0 = blockIdx.y * 128, n0 = blockIdx.x * 128;

  f32x4 acc[4][4] = {};

  for (int k0 = 0; k0 < K; k0 += 64) {
#pragma unroll
    for (int it = 0; it < 4; ++it) {
      int id = it * 256 + t;
      int r = id >> 3, c8 = (id & 7) << 3;
      gload_lds16(A + (size_t)(m0 + r) * K + k0 + c8, &As[id * 8]);
      gload_lds16(Bm + (size_t)(n0 + r) * K + k0 + c8, &Bs[id * 8]);
    }
    __syncthreads();

#pragma unroll
    for (int kk = 0; kk < 2; ++kk) {
      s16x8 af[4], bf[4];
#pragma unroll
      for (int i = 0; i < 4; ++i) {
        af[i] = *(const s16x8*)&As[(wm * 64 + i * 16 + lr) * 64 + kk * 32 + lk * 8];
        bf[i] = *(const s16x8*)&Bs[(wn * 64 + i * 16 + lr) * 64 + kk * 32 + lk * 8];
      }
#pragma unroll
      for (int i = 0; i < 4; ++i)
#pragma unroll
        for (int j = 0; j < 4; ++j)
          acc[i][j] = __builtin_amdgcn_mfma_f32_16x16x32_bf16(af[i], bf[j], acc[i][j], 0, 0, 0);
    }
    __syncthreads();
  }

#pragma unroll
  for (int i = 0; i < 4; ++i) {
    int row_b = m0 + wm * 64 + i * 16 + lk * 4;
#pragma unroll
    for (int j = 0; j < 4; ++j) {
      int col = n0 + wn * 64 + j * 16 + lr;
      float bv = BIAS ? bias[col] : 0.f;
#pragma unroll
      for (int r = 0; r < 4; ++r) {
        float v = acc[i][j][r] + bv;
        size_t off = (size_t)(row_b + r) * N + col;
        if constexpr (sizeof(OutT) == 2) ((u16*)C)[off] = f2bf(v);
        else                             ((float*)C)[off] = v;
      }
    }
  }
}

// ---------------- RoPE on Q and K in place (bf16) ----------------
__global__ void rope_qk(u16* __restrict__ Q, u16* __restrict__ Kt,
                        const float* __restrict__ cosp, const float* __restrict__ sinp) {
  int i = blockIdx.x * 256 + threadIdx.x;   // over S*H*64
  int d = i & 63;
  int h = (i >> 6) & 31;
  int s = i >> 11;
  float c = cosp[s * 128 + d], sn = sinp[s * 128 + d];
  size_t base = (size_t)s * 4096 + h * 128 + d;
  float q1 = bf2f(Q[base]), q2 = bf2f(Q[base + 64]);
  Q[base]      = f2bf(q1 * c - q2 * sn);
  Q[base + 64] = f2bf(q2 * c + q1 * sn);
  float k1 = bf2f(Kt[base]), k2 = bf2f(Kt[base + 64]);
  Kt[base]      = f2bf(k1 * c - k2 * sn);
  Kt[base + 64] = f2bf(k2 * c + k1 * sn);
}

// ---------------- Flash attention (causal): QBLK=128, KVBLK=64, 8 waves ----------------
__global__ __launch_bounds__(512) void flash_attn(
    const u16* __restrict__ Q, const u16* __restrict__ Kg, const u16* __restrict__ Vg,
    u16* __restrict__ Ctx)
{
  const int D = 4096;
  __shared__ u16 Ks[64 * 128];     // [kv][d-chunk], chunk XOR-swizzled by (kv&7)
  __shared__ u16 Vt[128 * 64];     // [d][kv], kv XOR-swizzled by (((d>>3)^d)&7)<<3
  __shared__ u16 Ps[8][16 * 64];   // per-wave P, col XOR-swizzled by ((q>>1)&7)<<3

  const int t = threadIdx.x, lane = t & 63, wid = t >> 6;
  const int lr = lane & 15, lk = lane >> 4;

  // XCD-chunked swizzle: each XCD gets 64 consecutive work-ids = 4 heads
  const int wg = blockIdx.x;                  // 0..511
  const int work = (wg & 7) * 64 + (wg >> 3);
  const int h = work >> 4;                    // 0..31
  const int bx = work & 15;                   // 0..15
  const int q0 = bx * 128;
  const int qw0 = q0 + wid * 16;

  // Q fragments (A-frag: row = lane&15, k chunk = lk*8)
  s16x8 qf[4];
#pragma unroll
  for (int kc = 0; kc < 4; ++kc)
    qf[kc] = *(const s16x8*)(Q + (size_t)(qw0 + lr) * D + h * 128 + kc * 32 + lk * 8);

  f32x4 o[8] = {};
  float m_r[4] = {-1e30f, -1e30f, -1e30f, -1e30f};
  float l_r[4] = {0.f, 0.f, 0.f, 0.f};

  const int ntiles = 2 * bx + 2;
  const float scale = 0.08838834764831845f;   // 1/sqrt(128)

  for (int kt = 0; kt < ntiles; ++kt) {
    const int kv0 = kt * 64;

    // --- stage K tile: 64x128 bf16 = 1024 chunks, gload_lds, src pre-swizzled
#pragma unroll
    for (int it = 0; it < 2; ++it) {
      int id = it * 512 + t;
      int kv = id >> 4, ch0 = id & 15;
      gload_lds16(Kg + (size_t)(kv0 + kv) * D + h * 128 + ((ch0 ^ (kv & 7)) << 3), &Ks[id * 8]);
    }
    // --- stage V transposed: thread handles kv pair (kv2,kv2+1) x 8 d's, u32 writes
    {
      int ch = t & 15, kvp = t >> 4;          // kvp 0..31
      int kv2 = kvp * 2;
      const u16* src = Vg + (size_t)(kv0 + kv2) * D + h * 128 + ch * 8;
      s16x8 v0 = *(const s16x8*)src;
      s16x8 v1 = *(const s16x8*)(src + D);
#pragma unroll
      for (int j = 0; j < 8; ++j) {
        int d = ch * 8 + j;
        int sw = ((ch ^ j) & 7) << 3;
        unsigned pr = (unsigned)(u16)v0[j] | ((unsigned)(u16)v1[j] << 16);
        *(unsigned*)&Vt[d * 64 + (kv2 ^ sw)] = pr;
      }
    }
    __syncthreads();

    if (kv0 <= qw0 + 15) {   // wave has at least one unmasked row
      const bool masked = (kv0 + 63 > qw0);

      // --- QK^T: S(16x64) for this wave's 16 q rows
      f32x4 st[4] = {};
      __builtin_amdgcn_s_setprio(1);
#pragma unroll
      for (int nt = 0; nt < 4; ++nt) {
        int kv = nt * 16 + lr;
        int sw = kv & 7;
#pragma unroll
        for (int kc = 0; kc < 4; ++kc) {
          s16x8 kf = *(const s16x8*)&Ks[kv * 128 + (((4 * kc + lk) ^ sw) << 3)];
          st[nt] = __builtin_amdgcn_mfma_f32_16x16x32_bf16(qf[kc], kf, st[nt], 0, 0, 0);
        }
      }
      __builtin_amdgcn_s_setprio(0);

      // --- online softmax (rows: q = qw0 + lk*4 + r; cols: kv = kv0 + nt*16 + lr)
      float pmax_[4];
#pragma unroll
      for (int r = 0; r < 4; ++r) {
        int q_r = qw0 + lk * 4 + r;
#pragma unroll
        for (int nt = 0; nt < 4; ++nt) {
          float sv = st[nt][r] * scale;
          if (masked && (kv0 + nt * 16 + lr > q_r)) sv = -1e30f;
          st[nt][r] = sv;
        }
        float pm = fmaxf(fmaxf(st[0][r], st[1][r]), fmaxf(st[2][r], st[3][r]));
        pm = fmaxf(pm, __shfl_xor(pm, 1));
        pm = fmaxf(pm, __shfl_xor(pm, 2));
        pm = fmaxf(pm, __shfl_xor(pm, 4));
        pm = fmaxf(pm, __shfl_xor(pm, 8));
        pmax_[r] = pm;
      }
      // defer-max: rescale only if some row grew past m + 8
      bool nr = (pmax_[0] > m_r[0] + 8.f) || (pmax_[1] > m_r[1] + 8.f) ||
                (pmax_[2] > m_r[2] + 8.f) || (pmax_[3] > m_r[3] + 8.f);
      if (__any(nr)) {
#pragma unroll
        for (int r = 0; r < 4; ++r) {
          float mn = fmaxf(m_r[r], pmax_[r]);
          float al = __expf(m_r[r] - mn);
          m_r[r] = mn; l_r[r] *= al;
#pragma unroll
          for (int nb = 0; nb < 8; ++nb) o[nb][r] *= al;
        }
      }
      // exp, row-sum, and P store (D-layout -> Ps, swizzled)
#pragma unroll
      for (int r = 0; r < 4; ++r) {
        int ql = lk * 4 + r;
        int swp = ((ql >> 1) & 7) << 3;
        float ps = 0.f;
#pragma unroll
        for (int nt = 0; nt < 4; ++nt) {
          float pv = __expf(st[nt][r] - m_r[r]);
          ps += pv;
          Ps[wid][ql * 64 + ((nt * 16 + lr) ^ swp)] = f2bf(pv);
        }
        ps += __shfl_xor(ps, 1);
        ps += __shfl_xor(ps, 2);
        ps += __shfl_xor(ps, 4);
        ps += __shfl_xor(ps, 8);
        l_r[r] += ps;
      }
      asm volatile("s_waitcnt lgkmcnt(0)" ::: "memory");

      // --- P A-frags (row = lane&15 = q, k chunk = lk*8 kv's)
      s16x8 pa[2];
#pragma unroll
      for (int ks = 0; ks < 2; ++ks) {
        int col = (ks * 32 + lk * 8) ^ (((lr >> 1) & 7) << 3);
        pa[ks] = *(const s16x8*)&Ps[wid][lr * 64 + col];
      }

      // --- PV: O(16x128) += P(16x64) * V(64x128)
      __builtin_amdgcn_s_setprio(1);
#pragma unroll
      for (int ks = 0; ks < 2; ++ks) {
#pragma unroll
        for (int nb = 0; nb < 8; ++nb) {
          int d = nb * 16 + lr;
          int g = (((d >> 3) ^ d) & 7) << 3;
          s16x8 vf = *(const s16x8*)&Vt[d * 64 + ((ks * 32 + lk * 8) ^ g)];
          o[nb] = __builtin_amdgcn_mfma_f32_16x16x32_bf16(pa[ks], vf, o[nb], 0, 0, 0);
        }
      }
      __builtin_amdgcn_s_setprio(0);
    }
    __syncthreads();
  }

  // --- normalize + write ctx (bf16)
#pragma unroll
  for (int r = 0; r < 4; ++r) {
    float inv = 1.f / l_r[r];
    int q_r = qw0 + lk * 4 + r;
#pragma unroll
    for (int nb = 0; nb < 8; ++nb)
      Ctx[(size_t)q_r * D + h * 128 + nb * 16 + lr] = f2bf(o[nb][r] * inv);
  }
}

// ---------------- launcher ----------------
extern "C" void kernel_launch(void* const* d_in, const int* in_sizes, int n_in,
                              void* d_out, int out_size, void* d_ws, size_t ws_size,
                              hipStream_t stream) {
  const int S = 2048, D = 4096, H = 32;
  const size_t SD = (size_t)S * D, DD = (size_t)D * D;

  const float* X  = (const float*)d_in[0];
  const float* Wq = (const float*)d_in[1];
  const float* Wk = (const float*)d_in[2];
  const float* Wv = (const float*)d_in[3];
  const float* Wo = (const float*)d_in[4];
  const float* bo = (const float*)d_in[5];
  const float* cs = (const float*)d_in[6];
  const float* sn = (const float*)d_in[7];

  u16* WB = (u16*)d_ws;
  u16* Xb = WB + DD;
  u16* Qb = Xb + SD;
  u16* Kb = Qb + SD;
  u16* Vb = Kb + SD;

  dim3 blk(256);
  dim3 gg(D / 128, S / 128);

  cvt_f32_bf16<<<(int)(SD / 1024), blk, 0, stream>>>(X, Xb, (int)SD);
  cvt_f32_bf16<<<(int)(DD / 1024), blk, 0, stream>>>(Wq, WB, (int)DD);
  gemm_bt<u16, false><<<gg, blk, 0, stream>>>(Xb, WB, Qb, nullptr, S, D, D);
  cvt_f32_bf16<<<(int)(DD / 1024), blk, 0, stream>>>(Wk, WB, (int)DD);
  gemm_bt<u16, false><<<gg, blk, 0, stream>>>(Xb, WB, Kb, nullptr, S, D, D);
  cvt_f32_bf16<<<(int)(DD / 1024), blk, 0, stream>>>(Wv, WB, (int)DD);
  gemm_bt<u16, false><<<gg, blk, 0, stream>>>(Xb, WB, Vb, nullptr, S, D, D);

  rope_qk<<<(S * H * 64) / 256, blk, 0, stream>>>(Qb, Kb, cs, sn);

  flash_attn<<<dim3(512), dim3(512), 0, stream>>>(Qb, Kb, Vb, Xb /*Ctx*/);

  cvt_f32_bf16<<<(int)(DD / 1024), blk, 0, stream>>>(Wo, WB, (int)DD);
  gemm_bt<float, true><<<gg, blk, 0, stream>>>(Xb, WB, (float*)d_out, bo, S, D, D);
}

// Round 3
// 589.821 us; speedup vs baseline: 1.2589x; 1.0958x over previous
//
#include <hip/hip_runtime.h>

typedef unsigned short u16;
typedef __attribute__((ext_vector_type(8))) short s16x8;
typedef __attribute__((ext_vector_type(4))) float f32x4;

__device__ __forceinline__ u16 f2bf(float f) {
  unsigned u = __float_as_uint(f);
  u += 0x7fffu + ((u >> 16) & 1u);   // RNE
  return (u16)(u >> 16);
}
__device__ __forceinline__ float bf2f(u16 h) {
  return __uint_as_float(((unsigned)h) << 16);
}

typedef __attribute__((address_space(1))) const void gvoid_t;
typedef __attribute__((address_space(3))) void lvoid_t;
__device__ __forceinline__ void gload_lds16(const void* g, void* l) {
  __builtin_amdgcn_global_load_lds((gvoid_t*)g, (lvoid_t*)l, 16, 0, 0);
}

// ---------------- f32 -> bf16 convert (vectorized) ----------------
__global__ void cvt_f32_bf16(const float* __restrict__ in, u16* __restrict__ out, int n) {
  int i = (blockIdx.x * 256 + threadIdx.x) * 4;
  if (i >= n) return;
  float4 v = *(const float4*)(in + i);
  ushort4 o;
  o.x = f2bf(v.x); o.y = f2bf(v.y); o.z = f2bf(v.z); o.w = f2bf(v.w);
  *(ushort4*)(out + i) = o;
}

// ---------------- GEMM: C[M,N] = A[M,K] * B[N,K]^T  (m97 structure) ----------------
template<typename OutT, bool BIAS>
__global__ __launch_bounds__(256) void gemm_bt(
    const u16* __restrict__ A, const u16* __restrict__ Bm,
    OutT* __restrict__ C, const float* __restrict__ bias,
    int M, int N, int K)
{
  __shared__ u16 As[128 * 64];
  __shared__ u16 Bs[128 * 64];

  const int t = threadIdx.x;
  const int lane = t & 63, wid = t >> 6;
  const int wm = wid >> 1, wn = wid & 1;
  const int lr = lane & 15, lk = lane >> 4;
  const int m0 = blockIdx.y * 128, n0 = blockIdx.x * 128;

  f32x4 acc[4][4] = {};

  for (int k0 = 0; k0 < K; k0 += 64) {
#pragma unroll
    for (int it = 0; it < 4; ++it) {
      int id = it * 256 + t;
      int r = id >> 3, c8 = (id & 7) << 3;
      gload_lds16(A + (size_t)(m0 + r) * K + k0 + c8, &As[id * 8]);
      gload_lds16(Bm + (size_t)(n0 + r) * K + k0 + c8, &Bs[id * 8]);
    }
    __syncthreads();

#pragma unroll
    for (int kk = 0; kk < 2; ++kk) {
      s16x8 af[4], bf[4];
#pragma unroll
      for (int i = 0; i < 4; ++i) {
        af[i] = *(const s16x8*)&As[(wm * 64 + i * 16 + lr) * 64 + kk * 32 + lk * 8];
        bf[i] = *(const s16x8*)&Bs[(wn * 64 + i * 16 + lr) * 64 + kk * 32 + lk * 8];
      }
#pragma unroll
      for (int i = 0; i < 4; ++i)
#pragma unroll
        for (int j = 0; j < 4; ++j)
          acc[i][j] = __builtin_amdgcn_mfma_f32_16x16x32_bf16(af[i], bf[j], acc[i][j], 0, 0, 0);
    }
    __syncthreads();
  }

#pragma unroll
  for (int i = 0; i < 4; ++i) {
    int row_b = m0 + wm * 64 + i * 16 + lk * 4;
#pragma unroll
    for (int j = 0; j < 4; ++j) {
      int col = n0 + wn * 64 + j * 16 + lr;
      float bv = BIAS ? bias[col] : 0.f;
#pragma unroll
      for (int r = 0; r < 4; ++r) {
        float v = acc[i][j][r] + bv;
        size_t off = (size_t)(row_b + r) * N + col;
        if constexpr (sizeof(OutT) == 2) ((u16*)C)[off] = f2bf(v);
        else                             ((float*)C)[off] = v;
      }
    }
  }
}

// ---------------- RoPE on Q and K in place (bf16) ----------------
__global__ void rope_qk(u16* __restrict__ Q, u16* __restrict__ Kt,
                        const float* __restrict__ cosp, const float* __restrict__ sinp) {
  int i = blockIdx.x * 256 + threadIdx.x;   // over S*H*64
  int d = i & 63;
  int h = (i >> 6) & 31;
  int s = i >> 11;
  float c = cosp[s * 128 + d], sn = sinp[s * 128 + d];
  size_t base = (size_t)s * 4096 + h * 128 + d;
  float q1 = bf2f(Q[base]), q2 = bf2f(Q[base + 64]);
  Q[base]      = f2bf(q1 * c - q2 * sn);
  Q[base + 64] = f2bf(q2 * c + q1 * sn);
  float k1 = bf2f(Kt[base]), k2 = bf2f(Kt[base + 64]);
  Kt[base]      = f2bf(k1 * c - k2 * sn);
  Kt[base + 64] = f2bf(k2 * c + k1 * sn);
}

// ---------------- Flash attention (causal): QBLK=128, KVBLK=64, 8 waves ----------------
// Double-buffered K/V staging, one barrier per tile, LPT work order within XCD.
__global__ __launch_bounds__(512) void flash_attn(
    const u16* __restrict__ Q, const u16* __restrict__ Kg, const u16* __restrict__ Vg,
    u16* __restrict__ Ctx)
{
  const int D = 4096;
  __shared__ u16 Ks[2][64 * 128];  // [kv][d-chunk], chunk XOR-swizzled by (kv&7)
  __shared__ u16 Vt[2][128 * 64];  // [d][kv], kv XOR-swizzled by (((d>>3)^d)&7)<<3
  __shared__ u16 Ps[8][16 * 64];   // per-wave P, col XOR-swizzled by ((q>>1)&7)<<3

  const int t = threadIdx.x, lane = t & 63, wid = t >> 6;
  const int lr = lane & 15, lk = lane >> 4;

  // XCD-chunked + LPT: within each XCD, longest blocks (largest bx) first.
  const int wg = blockIdx.x;              // 0..511
  const int xcd = wg & 7, j = wg >> 3;    // j 0..63 local
  const int bx = 15 - (j >> 2);           // 15,15,15,15,14,...
  const int h = xcd * 4 + (j & 3);        // 4 heads per XCD
  const int q0 = bx * 128;
  const int qw0 = q0 + wid * 16;

  // Q fragments (A-frag: row = lane&15, k chunk = lk*8)
  s16x8 qf[4];
#pragma unroll
  for (int kc = 0; kc < 4; ++kc)
    qf[kc] = *(const s16x8*)(Q + (size_t)(qw0 + lr) * D + h * 128 + kc * 32 + lk * 8);

  f32x4 o[8] = {};
  float m_r[4] = {-1e30f, -1e30f, -1e30f, -1e30f};
  float l_r[4] = {0.f, 0.f, 0.f, 0.f};

  const int ntiles = 2 * bx + 2;
  const float scale2 = 0.12751779f;       // (1/sqrt(128)) * log2(e) — exp2 domain

  const int ch = t & 15, kv2 = (t >> 4) * 2;   // V-staging: 2 kv rows x 8 d's per thread

  // ---- prologue: stage tile 0 into buffer 0
  {
    const u16* src = Vg + (size_t)kv2 * D + h * 128 + ch * 8;
    s16x8 a0 = *(const s16x8*)src;
    s16x8 a1 = *(const s16x8*)(src + D);
#pragma unroll
    for (int it = 0; it < 2; ++it) {
      int id = it * 512 + t;
      int kv = id >> 4, c0 = id & 15;
      gload_lds16(Kg + (size_t)kv * D + h * 128 + ((c0 ^ (kv & 7)) << 3), &Ks[0][id * 8]);
    }
#pragma unroll
    for (int jj = 0; jj < 8; ++jj) {
      int d = ch * 8 + jj;
      int sw = ((ch ^ jj) & 7) << 3;
      unsigned pr = (unsigned)(u16)a0[jj] | ((unsigned)(u16)a1[jj] << 16);
      *(unsigned*)&Vt[0][d * 64 + (kv2 ^ sw)] = pr;
    }
  }

  for (int kt = 0; kt < ntiles; ++kt) {
    const int b = kt & 1;
    const int kv0 = kt * 64;
    __syncthreads();                       // buffer b staged (drains vmcnt+lgkmcnt)

    // ---- issue next-tile staging (buffer b^1): V reg-loads first, then K gload_lds
    s16x8 a0, a1;
    const bool pf = (kt + 1 < ntiles);
    if (pf) {
      const u16* src = Vg + (size_t)(kv0 + 64 + kv2) * D + h * 128 + ch * 8;
      a0 = *(const s16x8*)src;
      a1 = *(const s16x8*)(src + D);
#pragma unroll
      for (int it = 0; it < 2; ++it) {
        int id = it * 512 + t;
        int kv = id >> 4, c0 = id & 15;
        gload_lds16(Kg + (size_t)(kv0 + 64 + kv) * D + h * 128 + ((c0 ^ (kv & 7)) << 3),
                    &Ks[b ^ 1][id * 8]);
      }
    }

    // ---- compute current tile from buffer b
    if (kv0 <= qw0 + 15) {
      const bool masked = (kv0 + 63 > qw0);

      f32x4 st[4] = {};
      __builtin_amdgcn_s_setprio(1);
#pragma unroll
      for (int nt = 0; nt < 4; ++nt) {
        int kv = nt * 16 + lr;
        int sw = kv & 7;
#pragma unroll
        for (int kc = 0; kc < 4; ++kc) {
          s16x8 kf = *(const s16x8*)&Ks[b][kv * 128 + (((4 * kc + lk) ^ sw) << 3)];
          st[nt] = __builtin_amdgcn_mfma_f32_16x16x32_bf16(qf[kc], kf, st[nt], 0, 0, 0);
        }
      }
      __builtin_amdgcn_s_setprio(0);

      // online softmax in exp2 domain (rows: q = qw0+lk*4+r; cols: kv = kv0+nt*16+lr)
      float pmax_[4];
#pragma unroll
      for (int r = 0; r < 4; ++r) {
        int q_r = qw0 + lk * 4 + r;
        if (masked) {
#pragma unroll
          for (int nt = 0; nt < 4; ++nt) {
            float sv = st[nt][r] * scale2;
            if (kv0 + nt * 16 + lr > q_r) sv = -1e30f;
            st[nt][r] = sv;
          }
        } else {
#pragma unroll
          for (int nt = 0; nt < 4; ++nt) st[nt][r] *= scale2;
        }
        float pm = fmaxf(fmaxf(st[0][r], st[1][r]), fmaxf(st[2][r], st[3][r]));
        pm = fmaxf(pm, __shfl_xor(pm, 1));
        pm = fmaxf(pm, __shfl_xor(pm, 2));
        pm = fmaxf(pm, __shfl_xor(pm, 4));
        pm = fmaxf(pm, __shfl_xor(pm, 8));
        pmax_[r] = pm;
      }
      bool nr = (pmax_[0] > m_r[0] + 8.f) || (pmax_[1] > m_r[1] + 8.f) ||
                (pmax_[2] > m_r[2] + 8.f) || (pmax_[3] > m_r[3] + 8.f);
      if (__any(nr)) {
#pragma unroll
        for (int r = 0; r < 4; ++r) {
          float mn = fmaxf(m_r[r], pmax_[r]);
          float al = __builtin_amdgcn_exp2f(m_r[r] - mn);
          m_r[r] = mn; l_r[r] *= al;
#pragma unroll
          for (int nb = 0; nb < 8; ++nb) o[nb][r] *= al;
        }
      }
#pragma unroll
      for (int r = 0; r < 4; ++r) {
        int ql = lk * 4 + r;
        int swp = ((ql >> 1) & 7) << 3;
        float ps = 0.f;
#pragma unroll
        for (int nt = 0; nt < 4; ++nt) {
          float pv = __builtin_amdgcn_exp2f(st[nt][r] - m_r[r]);
          ps += pv;
          Ps[wid][ql * 64 + ((nt * 16 + lr) ^ swp)] = f2bf(pv);
        }
        ps += __shfl_xor(ps, 1);
        ps += __shfl_xor(ps, 2);
        ps += __shfl_xor(ps, 4);
        ps += __shfl_xor(ps, 8);
        l_r[r] += ps;
      }
      asm volatile("s_waitcnt lgkmcnt(0)" ::: "memory");

      // P A-frags (row = lane&15 = q, k chunk = lk*8 kv's)
      s16x8 pa[2];
#pragma unroll
      for (int ks = 0; ks < 2; ++ks) {
        int col = (ks * 32 + lk * 8) ^ (((lr >> 1) & 7) << 3);
        pa[ks] = *(const s16x8*)&Ps[wid][lr * 64 + col];
      }

      // PV: O(16x128) += P(16x64) * V(64x128)
      __builtin_amdgcn_s_setprio(1);
#pragma unroll
      for (int ks = 0; ks < 2; ++ks) {
#pragma unroll
        for (int nb = 0; nb < 8; ++nb) {
          int d = nb * 16 + lr;
          int g = (((d >> 3) ^ d) & 7) << 3;
          s16x8 vf = *(const s16x8*)&Vt[b][d * 64 + ((ks * 32 + lk * 8) ^ g)];
          o[nb] = __builtin_amdgcn_mfma_f32_16x16x32_bf16(pa[ks], vf, o[nb], 0, 0, 0);
        }
      }
      __builtin_amdgcn_s_setprio(0);
    }

    // ---- finish next-tile V staging (regs -> LDS buf b^1)
    if (pf) {
#pragma unroll
      for (int jj = 0; jj < 8; ++jj) {
        int d = ch * 8 + jj;
        int sw = ((ch ^ jj) & 7) << 3;
        unsigned pr = (unsigned)(u16)a0[jj] | ((unsigned)(u16)a1[jj] << 16);
        *(unsigned*)&Vt[b ^ 1][d * 64 + (kv2 ^ sw)] = pr;
      }
    }
  }

  // ---- normalize + write ctx (bf16)
#pragma unroll
  for (int r = 0; r < 4; ++r) {
    float inv = 1.f / l_r[r];
    int q_r = qw0 + lk * 4 + r;
#pragma unroll
    for (int nb = 0; nb < 8; ++nb)
      Ctx[(size_t)q_r * D + h * 128 + nb * 16 + lr] = f2bf(o[nb][r] * inv);
  }
}

// ---------------- launcher ----------------
extern "C" void kernel_launch(void* const* d_in, const int* in_sizes, int n_in,
                              void* d_out, int out_size, void* d_ws, size_t ws_size,
                              hipStream_t stream) {
  const int S = 2048, D = 4096, H = 32;
  const size_t SD = (size_t)S * D, DD = (size_t)D * D;

  const float* X  = (const float*)d_in[0];
  const float* Wq = (const float*)d_in[1];
  const float* Wk = (const float*)d_in[2];
  const float* Wv = (const float*)d_in[3];
  const float* Wo = (const float*)d_in[4];
  const float* bo = (const float*)d_in[5];
  const float* cs = (const float*)d_in[6];
  const float* sn = (const float*)d_in[7];

  u16* WB = (u16*)d_ws;
  u16* Xb = WB + DD;
  u16* Qb = Xb + SD;
  u16* Kb = Qb + SD;
  u16* Vb = Kb + SD;

  dim3 blk(256);
  dim3 gg(D / 128, S / 128);

  cvt_f32_bf16<<<(int)(SD / 1024), blk, 0, stream>>>(X, Xb, (int)SD);
  cvt_f32_bf16<<<(int)(DD / 1024), blk, 0, stream>>>(Wq, WB, (int)DD);
  gemm_bt<u16, false><<<gg, blk, 0, stream>>>(Xb, WB, Qb, nullptr, S, D, D);
  cvt_f32_bf16<<<(int)(DD / 1024), blk, 0, stream>>>(Wk, WB, (int)DD);
  gemm_bt<u16, false><<<gg, blk, 0, stream>>>(Xb, WB, Kb, nullptr, S, D, D);
  cvt_f32_bf16<<<(int)(DD / 1024), blk, 0, stream>>>(Wv, WB, (int)DD);
  gemm_bt<u16, false><<<gg, blk, 0, stream>>>(Xb, WB, Vb, nullptr, S, D, D);

  rope_qk<<<(S * H * 64) / 256, blk, 0, stream>>>(Qb, Kb, cs, sn);

  flash_attn<<<dim3(512), dim3(512), 0, stream>>>(Qb, Kb, Vb, Xb /*Ctx*/);

  cvt_f32_bf16<<<(int)(DD / 1024), blk, 0, stream>>>(Wo, WB, (int)DD);
  gemm_bt<float, true><<<gg, blk, 0, stream>>>(Xb, WB, (float*)d_out, bo, S, D, D);
}

// Round 4
// 580.971 us; speedup vs baseline: 1.2781x; 1.0152x over previous
//
#include <hip/hip_runtime.h>

typedef unsigned short u16;
typedef __attribute__((ext_vector_type(8))) short s16x8;
typedef __attribute__((ext_vector_type(4))) float f32x4;

__device__ __forceinline__ u16 f2bf(float f) {
  unsigned u = __float_as_uint(f);
  u += 0x7fffu + ((u >> 16) & 1u);   // RNE
  return (u16)(u >> 16);
}
__device__ __forceinline__ float bf2f(u16 h) {
  return __uint_as_float(((unsigned)h) << 16);
}

typedef __attribute__((address_space(1))) const void gvoid_t;
typedef __attribute__((address_space(3))) void lvoid_t;
__device__ __forceinline__ void gload_lds16(const void* g, void* l) {
  __builtin_amdgcn_global_load_lds((gvoid_t*)g, (lvoid_t*)l, 16, 0, 0);
}

// ---------------- f32 -> bf16 convert (vectorized) ----------------
__global__ void cvt_f32_bf16(const float* __restrict__ in, u16* __restrict__ out, int n) {
  int i = (blockIdx.x * 256 + threadIdx.x) * 4;
  if (i >= n) return;
  float4 v = *(const float4*)(in + i);
  ushort4 o;
  o.x = f2bf(v.x); o.y = f2bf(v.y); o.z = f2bf(v.z); o.w = f2bf(v.w);
  *(ushort4*)(out + i) = o;
}

// ---------------- GEMM v2: C[M,N] = A[M,K]*B[N,K]^T ----------------
// BM=128, BN=256, BK=64, 512 thr (8 waves 2Mx4N, per-wave 64x64).
// Triple-buffered LDS (144KB), 1 raw barrier/K-tile, counted vmcnt(6),
// T2 XOR swizzle (pre-swizzled gload src + swizzled ds_read), T5 setprio.
template<typename OutT, bool BIAS>
__global__ __launch_bounds__(512, 2) void gemm_bt2(
    const u16* __restrict__ A, const u16* __restrict__ Bm,
    OutT* __restrict__ C, const float* __restrict__ bias,
    int M, int N, int K)
{
  __shared__ u16 As[3][128 * 64];
  __shared__ u16 Bs[3][256 * 64];

  const int t = threadIdx.x;
  const int lane = t & 63, wid = t >> 6;
  const int wm = wid >> 2, wn = wid & 3;
  const int lr = lane & 15, lk = lane >> 4;

  // XCD swizzle: 256 blocks = 8 XCD x (16 m-blocks x 2 n-blocks)
  const int wg = blockIdx.x;
  const int xcd = wg & 7, j = wg >> 3;
  const int m0 = (j & 15) * 128;
  const int n0 = ((xcd << 1) | (j >> 4)) * 256;

  const int nt = K >> 6;

  f32x4 acc[4][4] = {};

#define STAGE(KT)                                                              \
  {                                                                            \
    const int bu_ = ((unsigned)(KT)) % 3u;                                     \
    const int k0_ = (KT) << 6;                                                 \
    _Pragma("unroll")                                                          \
    for (int it = 0; it < 2; ++it) {                                           \
      int id = it * 512 + t;                                                   \
      int r = id >> 3, c0 = id & 7;                                            \
      gload_lds16(A + (size_t)(m0 + r) * K + k0_ + ((c0 ^ (r & 7)) << 3),      \
                  &As[bu_][id * 8]);                                           \
    }                                                                          \
    _Pragma("unroll")                                                          \
    for (int it = 0; it < 4; ++it) {                                           \
      int id = it * 512 + t;                                                   \
      int r = id >> 3, c0 = id & 7;                                            \
      gload_lds16(Bm + (size_t)(n0 + r) * K + k0_ + ((c0 ^ (r & 7)) << 3),     \
                  &Bs[bu_][id * 8]);                                           \
    }                                                                          \
  }

  // prologue: tiles 0,1 in flight; wait for tile 0 (6 of 12 retire, in-order)
  STAGE(0);
  STAGE(1);
  asm volatile("s_waitcnt vmcnt(6)" ::: "memory");
  __builtin_amdgcn_s_barrier();

  for (int kt = 0; kt < nt; ++kt) {
    const int bu = ((unsigned)kt) % 3u;
    if (kt + 2 < nt) STAGE(kt + 2);

#pragma unroll
    for (int ks = 0; ks < 2; ++ks) {
      s16x8 af[4], bf[4];
#pragma unroll
      for (int i = 0; i < 4; ++i) {
        int ra = wm * 64 + i * 16 + lr;
        af[i] = *(const s16x8*)&As[bu][ra * 64 + (((ks * 4 + lk) ^ (ra & 7)) << 3)];
        int rb = wn * 64 + i * 16 + lr;
        bf[i] = *(const s16x8*)&Bs[bu][rb * 64 + (((ks * 4 + lk) ^ (rb & 7)) << 3)];
      }
      asm volatile("s_waitcnt lgkmcnt(0)" ::: "memory");
      __builtin_amdgcn_sched_barrier(0);
      __builtin_amdgcn_s_setprio(1);
#pragma unroll
      for (int i = 0; i < 4; ++i)
#pragma unroll
        for (int jn = 0; jn < 4; ++jn)
          acc[i][jn] = __builtin_amdgcn_mfma_f32_16x16x32_bf16(af[i], bf[jn], acc[i][jn], 0, 0, 0);
      __builtin_amdgcn_s_setprio(0);
    }

    // counted wait: kt+2's 6 loads may remain in flight; kt+1 fully landed
    if (kt + 2 < nt)       { asm volatile("s_waitcnt vmcnt(6)" ::: "memory"); }
    else if (kt + 2 == nt) { asm volatile("s_waitcnt vmcnt(0)" ::: "memory"); }
    if (kt + 1 < nt) __builtin_amdgcn_s_barrier();
  }
#undef STAGE

  // epilogue: D layout col=lane&15 (B-row), row=(lane>>4)*4+reg (A-row)
#pragma unroll
  for (int i = 0; i < 4; ++i) {
    int row_b = m0 + wm * 64 + i * 16 + lk * 4;
#pragma unroll
    for (int jn = 0; jn < 4; ++jn) {
      int col = n0 + wn * 64 + jn * 16 + lr;
      float bv = BIAS ? bias[col] : 0.f;
#pragma unroll
      for (int r = 0; r < 4; ++r) {
        float v = acc[i][jn][r] + bv;
        size_t off = (size_t)(row_b + r) * N + col;
        if constexpr (sizeof(OutT) == 2) ((u16*)C)[off] = f2bf(v);
        else                             ((float*)C)[off] = v;
      }
    }
  }
}

// ---------------- RoPE on Q and K in place (bf16) ----------------
__global__ void rope_qk(u16* __restrict__ Q, u16* __restrict__ Kt,
                        const float* __restrict__ cosp, const float* __restrict__ sinp) {
  int i = blockIdx.x * 256 + threadIdx.x;   // over S*H*64
  int d = i & 63;
  int h = (i >> 6) & 31;
  int s = i >> 11;
  float c = cosp[s * 128 + d], sn = sinp[s * 128 + d];
  size_t base = (size_t)s * 4096 + h * 128 + d;
  float q1 = bf2f(Q[base]), q2 = bf2f(Q[base + 64]);
  Q[base]      = f2bf(q1 * c - q2 * sn);
  Q[base + 64] = f2bf(q2 * c + q1 * sn);
  float k1 = bf2f(Kt[base]), k2 = bf2f(Kt[base + 64]);
  Kt[base]      = f2bf(k1 * c - k2 * sn);
  Kt[base + 64] = f2bf(k2 * c + k1 * sn);
}

// ---------------- Flash attention (causal): QBLK=128, KVBLK=64, 8 waves ----------------
__global__ __launch_bounds__(512) void flash_attn(
    const u16* __restrict__ Q, const u16* __restrict__ Kg, const u16* __restrict__ Vg,
    u16* __restrict__ Ctx)
{
  const int D = 4096;
  __shared__ u16 Ks[2][64 * 128];  // [kv][d-chunk], chunk XOR-swizzled by (kv&7)
  __shared__ u16 Vt[2][128 * 64];  // [d][kv], kv XOR-swizzled by (((d>>3)^d)&7)<<3
  __shared__ u16 Ps[8][16 * 64];   // per-wave P, col XOR-swizzled by ((q>>1)&7)<<3

  const int t = threadIdx.x, lane = t & 63, wid = t >> 6;
  const int lr = lane & 15, lk = lane >> 4;

  const int wg = blockIdx.x;              // 0..511
  const int xcd = wg & 7, j = wg >> 3;    // j 0..63 local
  const int bx = 15 - (j >> 2);           // LPT: longest first
  const int h = xcd * 4 + (j & 3);        // 4 heads per XCD
  const int q0 = bx * 128;
  const int qw0 = q0 + wid * 16;

  s16x8 qf[4];
#pragma unroll
  for (int kc = 0; kc < 4; ++kc)
    qf[kc] = *(const s16x8*)(Q + (size_t)(qw0 + lr) * D + h * 128 + kc * 32 + lk * 8);

  f32x4 o[8] = {};
  float m_r[4] = {-1e30f, -1e30f, -1e30f, -1e30f};
  float l_r[4] = {0.f, 0.f, 0.f, 0.f};

  const int ntiles = 2 * bx + 2;
  const float scale2 = 0.12751779f;       // (1/sqrt(128)) * log2(e)

  const int ch = t & 15, kv2 = (t >> 4) * 2;

  {
    const u16* src = Vg + (size_t)kv2 * D + h * 128 + ch * 8;
    s16x8 a0 = *(const s16x8*)src;
    s16x8 a1 = *(const s16x8*)(src + D);
#pragma unroll
    for (int it = 0; it < 2; ++it) {
      int id = it * 512 + t;
      int kv = id >> 4, c0 = id & 15;
      gload_lds16(Kg + (size_t)kv * D + h * 128 + ((c0 ^ (kv & 7)) << 3), &Ks[0][id * 8]);
    }
#pragma unroll
    for (int jj = 0; jj < 8; ++jj) {
      int d = ch * 8 + jj;
      int sw = ((ch ^ jj) & 7) << 3;
      unsigned pr = (unsigned)(u16)a0[jj] | ((unsigned)(u16)a1[jj] << 16);
      *(unsigned*)&Vt[0][d * 64 + (kv2 ^ sw)] = pr;
    }
  }

  for (int kt = 0; kt < ntiles; ++kt) {
    const int b = kt & 1;
    const int kv0 = kt * 64;
    __syncthreads();

    s16x8 a0, a1;
    const bool pf = (kt + 1 < ntiles);
    if (pf) {
      const u16* src = Vg + (size_t)(kv0 + 64 + kv2) * D + h * 128 + ch * 8;
      a0 = *(const s16x8*)src;
      a1 = *(const s16x8*)(src + D);
#pragma unroll
      for (int it = 0; it < 2; ++it) {
        int id = it * 512 + t;
        int kv = id >> 4, c0 = id & 15;
        gload_lds16(Kg + (size_t)(kv0 + 64 + kv) * D + h * 128 + ((c0 ^ (kv & 7)) << 3),
                    &Ks[b ^ 1][id * 8]);
      }
    }

    if (kv0 <= qw0 + 15) {
      const bool masked = (kv0 + 63 > qw0);

      f32x4 st[4] = {};
      __builtin_amdgcn_s_setprio(1);
#pragma unroll
      for (int nt = 0; nt < 4; ++nt) {
        int kv = nt * 16 + lr;
        int sw = kv & 7;
#pragma unroll
        for (int kc = 0; kc < 4; ++kc) {
          s16x8 kf = *(const s16x8*)&Ks[b][kv * 128 + (((4 * kc + lk) ^ sw) << 3)];
          st[nt] = __builtin_amdgcn_mfma_f32_16x16x32_bf16(qf[kc], kf, st[nt], 0, 0, 0);
        }
      }
      __builtin_amdgcn_s_setprio(0);

      float pmax_[4];
#pragma unroll
      for (int r = 0; r < 4; ++r) {
        int q_r = qw0 + lk * 4 + r;
        if (masked) {
#pragma unroll
          for (int nt = 0; nt < 4; ++nt) {
            float sv = st[nt][r] * scale2;
            if (kv0 + nt * 16 + lr > q_r) sv = -1e30f;
            st[nt][r] = sv;
          }
        } else {
#pragma unroll
          for (int nt = 0; nt < 4; ++nt) st[nt][r] *= scale2;
        }
        float pm = fmaxf(fmaxf(st[0][r], st[1][r]), fmaxf(st[2][r], st[3][r]));
        pm = fmaxf(pm, __shfl_xor(pm, 1));
        pm = fmaxf(pm, __shfl_xor(pm, 2));
        pm = fmaxf(pm, __shfl_xor(pm, 4));
        pm = fmaxf(pm, __shfl_xor(pm, 8));
        pmax_[r] = pm;
      }
      bool nr = (pmax_[0] > m_r[0] + 8.f) || (pmax_[1] > m_r[1] + 8.f) ||
                (pmax_[2] > m_r[2] + 8.f) || (pmax_[3] > m_r[3] + 8.f);
      if (__any(nr)) {
#pragma unroll
        for (int r = 0; r < 4; ++r) {
          float mn = fmaxf(m_r[r], pmax_[r]);
          float al = __builtin_amdgcn_exp2f(m_r[r] - mn);
          m_r[r] = mn; l_r[r] *= al;
#pragma unroll
          for (int nb = 0; nb < 8; ++nb) o[nb][r] *= al;
        }
      }
#pragma unroll
      for (int r = 0; r < 4; ++r) {
        int ql = lk * 4 + r;
        int swp = ((ql >> 1) & 7) << 3;
        float ps = 0.f;
#pragma unroll
        for (int nt = 0; nt < 4; ++nt) {
          float pv = __builtin_amdgcn_exp2f(st[nt][r] - m_r[r]);
          ps += pv;
          Ps[wid][ql * 64 + ((nt * 16 + lr) ^ swp)] = f2bf(pv);
        }
        ps += __shfl_xor(ps, 1);
        ps += __shfl_xor(ps, 2);
        ps += __shfl_xor(ps, 4);
        ps += __shfl_xor(ps, 8);
        l_r[r] += ps;
      }
      asm volatile("s_waitcnt lgkmcnt(0)" ::: "memory");

      s16x8 pa[2];
#pragma unroll
      for (int ks = 0; ks < 2; ++ks) {
        int col = (ks * 32 + lk * 8) ^ (((lr >> 1) & 7) << 3);
        pa[ks] = *(const s16x8*)&Ps[wid][lr * 64 + col];
      }

      __builtin_amdgcn_s_setprio(1);
#pragma unroll
      for (int ks = 0; ks < 2; ++ks) {
#pragma unroll
        for (int nb = 0; nb < 8; ++nb) {
          int d = nb * 16 + lr;
          int g = (((d >> 3) ^ d) & 7) << 3;
          s16x8 vf = *(const s16x8*)&Vt[b][d * 64 + ((ks * 32 + lk * 8) ^ g)];
          o[nb] = __builtin_amdgcn_mfma_f32_16x16x32_bf16(pa[ks], vf, o[nb], 0, 0, 0);
        }
      }
      __builtin_amdgcn_s_setprio(0);
    }

    if (pf) {
#pragma unroll
      for (int jj = 0; jj < 8; ++jj) {
        int d = ch * 8 + jj;
        int sw = ((ch ^ jj) & 7) << 3;
        unsigned pr = (unsigned)(u16)a0[jj] | ((unsigned)(u16)a1[jj] << 16);
        *(unsigned*)&Vt[b ^ 1][d * 64 + (kv2 ^ sw)] = pr;
      }
    }
  }

#pragma unroll
  for (int r = 0; r < 4; ++r) {
    float inv = 1.f / l_r[r];
    int q_r = qw0 + lk * 4 + r;
#pragma unroll
    for (int nb = 0; nb < 8; ++nb)
      Ctx[(size_t)q_r * D + h * 128 + nb * 16 + lr] = f2bf(o[nb][r] * inv);
  }
}

// ---------------- launcher ----------------
extern "C" void kernel_launch(void* const* d_in, const int* in_sizes, int n_in,
                              void* d_out, int out_size, void* d_ws, size_t ws_size,
                              hipStream_t stream) {
  const int S = 2048, D = 4096, H = 32;
  const size_t SD = (size_t)S * D, DD = (size_t)D * D;

  const float* X  = (const float*)d_in[0];
  const float* Wq = (const float*)d_in[1];
  const float* Wk = (const float*)d_in[2];
  const float* Wv = (const float*)d_in[3];
  const float* Wo = (const float*)d_in[4];
  const float* bo = (const float*)d_in[5];
  const float* cs = (const float*)d_in[6];
  const float* sn = (const float*)d_in[7];

  u16* WB = (u16*)d_ws;
  u16* Xb = WB + DD;
  u16* Qb = Xb + SD;
  u16* Kb = Qb + SD;
  u16* Vb = Kb + SD;

  dim3 blk(256);
  dim3 g2(256);      // (2048/128) x (4096/256)
  dim3 b2(512);

  cvt_f32_bf16<<<(int)(SD / 1024), blk, 0, stream>>>(X, Xb, (int)SD);
  cvt_f32_bf16<<<(int)(DD / 1024), blk, 0, stream>>>(Wq, WB, (int)DD);
  gemm_bt2<u16, false><<<g2, b2, 0, stream>>>(Xb, WB, Qb, nullptr, S, D, D);
  cvt_f32_bf16<<<(int)(DD / 1024), blk, 0, stream>>>(Wk, WB, (int)DD);
  gemm_bt2<u16, false><<<g2, b2, 0, stream>>>(Xb, WB, Kb, nullptr, S, D, D);
  cvt_f32_bf16<<<(int)(DD / 1024), blk, 0, stream>>>(Wv, WB, (int)DD);
  gemm_bt2<u16, false><<<g2, b2, 0, stream>>>(Xb, WB, Vb, nullptr, S, D, D);

  rope_qk<<<(S * H * 64) / 256, blk, 0, stream>>>(Qb, Kb, cs, sn);

  flash_attn<<<dim3(512), dim3(512), 0, stream>>>(Qb, Kb, Vb, Xb /*Ctx*/);

  cvt_f32_bf16<<<(int)(DD / 1024), blk, 0, stream>>>(Wo, WB, (int)DD);
  gemm_bt2<float, true><<<g2, b2, 0, stream>>>(Xb, WB, (float*)d_out, bo, S, D, D);
}

// Round 5
// 576.575 us; speedup vs baseline: 1.2878x; 1.0076x over previous
//
#include <hip/hip_runtime.h>

typedef unsigned short u16;
typedef __attribute__((ext_vector_type(8))) short s16x8;
typedef __attribute__((ext_vector_type(4))) float f32x4;

__device__ __forceinline__ u16 f2bf(float f) {
  unsigned u = __float_as_uint(f);
  u += 0x7fffu + ((u >> 16) & 1u);   // RNE
  return (u16)(u >> 16);
}
__device__ __forceinline__ float bf2f(u16 h) {
  return __uint_as_float(((unsigned)h) << 16);
}

typedef __attribute__((address_space(1))) const void gvoid_t;
typedef __attribute__((address_space(3))) void lvoid_t;
__device__ __forceinline__ void gload_lds16(const void* g, void* l) {
  __builtin_amdgcn_global_load_lds((gvoid_t*)g, (lvoid_t*)l, 16, 0, 0);
}

// ---------------- f32 -> bf16 convert (vectorized) ----------------
__global__ void cvt_f32_bf16(const float* __restrict__ in, u16* __restrict__ out, int n) {
  int i = (blockIdx.x * 256 + threadIdx.x) * 4;
  if (i >= n) return;
  float4 v = *(const float4*)(in + i);
  ushort4 o;
  o.x = f2bf(v.x); o.y = f2bf(v.y); o.z = f2bf(v.z); o.w = f2bf(v.w);
  *(ushort4*)(out + i) = o;
}

// ---------------- GEMM v2: C[M,N] = A[M,K]*B[N,K]^T ----------------
// BM=128, BN=256, BK=64, 512 thr (8 waves 2Mx4N, per-wave 64x64).
// Triple-buffered LDS (144KB), 1 raw barrier/K-tile, counted vmcnt(6),
// T2 XOR swizzle, T5 setprio. Compiler-free inner schedule (no asm pinning
// inside the tile — m141 lesson); one lgkmcnt(0) at tile boundary for the
// (kt+3)%3==bu buffer-reuse hazard.
template<typename OutT, bool BIAS>
__global__ __launch_bounds__(512) void gemm_bt2(
    const u16* __restrict__ A, const u16* __restrict__ Bm,
    OutT* __restrict__ C, const float* __restrict__ bias,
    int M, int N, int K)
{
  __shared__ u16 As[3][128 * 64];
  __shared__ u16 Bs[3][256 * 64];

  const int t = threadIdx.x;
  const int lane = t & 63, wid = t >> 6;
  const int wm = wid >> 2, wn = wid & 3;
  const int lr = lane & 15, lk = lane >> 4;

  // XCD swizzle: 256 blocks = 8 XCD x (16 m-blocks x 2 n-blocks)
  const int wg = blockIdx.x;
  const int xcd = wg & 7, j = wg >> 3;
  const int m0 = (j & 15) * 128;
  const int n0 = ((xcd << 1) | (j >> 4)) * 256;

  const int nt = K >> 6;

  f32x4 acc[4][4] = {};

#define STAGE(KT)                                                              \
  {                                                                            \
    const int bu_ = ((unsigned)(KT)) % 3u;                                     \
    const int k0_ = (KT) << 6;                                                 \
    _Pragma("unroll")                                                          \
    for (int it = 0; it < 2; ++it) {                                           \
      int id = it * 512 + t;                                                   \
      int r = id >> 3, c0 = id & 7;                                            \
      gload_lds16(A + (size_t)(m0 + r) * K + k0_ + ((c0 ^ (r & 7)) << 3),      \
                  &As[bu_][id * 8]);                                           \
    }                                                                          \
    _Pragma("unroll")                                                          \
    for (int it = 0; it < 4; ++it) {                                           \
      int id = it * 512 + t;                                                   \
      int r = id >> 3, c0 = id & 7;                                            \
      gload_lds16(Bm + (size_t)(n0 + r) * K + k0_ + ((c0 ^ (r & 7)) << 3),     \
                  &Bs[bu_][id * 8]);                                           \
    }                                                                          \
  }

  // prologue: tiles 0,1 in flight (12 loads); vmcnt(6) -> tile 0 landed
  STAGE(0);
  STAGE(1);
  asm volatile("s_waitcnt vmcnt(6)" ::: "memory");
  __builtin_amdgcn_s_barrier();
  __builtin_amdgcn_sched_barrier(0);

  for (int kt = 0; kt < nt; ++kt) {
    const int bu = ((unsigned)kt) % 3u;
    if (kt + 2 < nt) STAGE(kt + 2);

    __builtin_amdgcn_s_setprio(1);
#pragma unroll
    for (int ks = 0; ks < 2; ++ks) {
      s16x8 af[4], bf[4];
#pragma unroll
      for (int i = 0; i < 4; ++i) {
        int ra = wm * 64 + i * 16 + lr;
        af[i] = *(const s16x8*)&As[bu][ra * 64 + (((ks * 4 + lk) ^ (ra & 7)) << 3)];
        int rb = wn * 64 + i * 16 + lr;
        bf[i] = *(const s16x8*)&Bs[bu][rb * 64 + (((ks * 4 + lk) ^ (rb & 7)) << 3)];
      }
#pragma unroll
      for (int i = 0; i < 4; ++i)
#pragma unroll
        for (int jn = 0; jn < 4; ++jn)
          acc[i][jn] = __builtin_amdgcn_mfma_f32_16x16x32_bf16(af[i], bf[jn], acc[i][jn], 0, 0, 0);
    }
    __builtin_amdgcn_s_setprio(0);

    // tile boundary: own ds_reads drained (free in steady state), counted vmcnt
    asm volatile("s_waitcnt lgkmcnt(0)" ::: "memory");
    if (kt + 2 < nt)       { asm volatile("s_waitcnt vmcnt(6)" ::: "memory"); }
    else if (kt + 2 == nt) { asm volatile("s_waitcnt vmcnt(0)" ::: "memory"); }
    if (kt + 1 < nt) {
      __builtin_amdgcn_s_barrier();
      __builtin_amdgcn_sched_barrier(0);
    }
  }
#undef STAGE

  // epilogue: D layout col=lane&15 (B-row), row=(lane>>4)*4+reg (A-row)
#pragma unroll
  for (int i = 0; i < 4; ++i) {
    int row_b = m0 + wm * 64 + i * 16 + lk * 4;
#pragma unroll
    for (int jn = 0; jn < 4; ++jn) {
      int col = n0 + wn * 64 + jn * 16 + lr;
      float bv = BIAS ? bias[col] : 0.f;
#pragma unroll
      for (int r = 0; r < 4; ++r) {
        float v = acc[i][jn][r] + bv;
        size_t off = (size_t)(row_b + r) * N + col;
        if constexpr (sizeof(OutT) == 2) ((u16*)C)[off] = f2bf(v);
        else                             ((float*)C)[off] = v;
      }
    }
  }
}

// ---------------- RoPE on Q and K in place (bf16) ----------------
__global__ void rope_qk(u16* __restrict__ Q, u16* __restrict__ Kt,
                        const float* __restrict__ cosp, const float* __restrict__ sinp) {
  int i = blockIdx.x * 256 + threadIdx.x;   // over S*H*64
  int d = i & 63;
  int h = (i >> 6) & 31;
  int s = i >> 11;
  float c = cosp[s * 128 + d], sn = sinp[s * 128 + d];
  size_t base = (size_t)s * 4096 + h * 128 + d;
  float q1 = bf2f(Q[base]), q2 = bf2f(Q[base + 64]);
  Q[base]      = f2bf(q1 * c - q2 * sn);
  Q[base + 64] = f2bf(q2 * c + q1 * sn);
  float k1 = bf2f(Kt[base]), k2 = bf2f(Kt[base + 64]);
  Kt[base]      = f2bf(k1 * c - k2 * sn);
  Kt[base + 64] = f2bf(k2 * c + k1 * sn);
}

// ---------------- Flash attention (causal): QBLK=128, KVBLK=64, 8 waves ----------------
__global__ __launch_bounds__(512) void flash_attn(
    const u16* __restrict__ Q, const u16* __restrict__ Kg, const u16* __restrict__ Vg,
    u16* __restrict__ Ctx)
{
  const int D = 4096;
  __shared__ u16 Ks[2][64 * 128];  // [kv][d-chunk], chunk XOR-swizzled by (kv&7)
  __shared__ u16 Vt[2][128 * 64];  // [d][kv], kv XOR-swizzled by (((d>>3)^d)&7)<<3
  __shared__ u16 Ps[8][16 * 64];   // per-wave P, col XOR-swizzled by ((q>>1)&7)<<3

  const int t = threadIdx.x, lane = t & 63, wid = t >> 6;
  const int lr = lane & 15, lk = lane >> 4;

  const int wg = blockIdx.x;              // 0..511
  const int xcd = wg & 7, j = wg >> 3;    // j 0..63 local
  const int bx = 15 - (j >> 2);           // LPT: longest first
  const int h = xcd * 4 + (j & 3);        // 4 heads per XCD
  const int q0 = bx * 128;
  const int qw0 = q0 + wid * 16;

  s16x8 qf[4];
#pragma unroll
  for (int kc = 0; kc < 4; ++kc)
    qf[kc] = *(const s16x8*)(Q + (size_t)(qw0 + lr) * D + h * 128 + kc * 32 + lk * 8);

  f32x4 o[8] = {};
  float m_r[4] = {-1e30f, -1e30f, -1e30f, -1e30f};
  float l_r[4] = {0.f, 0.f, 0.f, 0.f};

  const int ntiles = 2 * bx + 2;
  const float scale2 = 0.12751779f;       // (1/sqrt(128)) * log2(e)

  const int ch = t & 15, kv2 = (t >> 4) * 2;

  {
    const u16* src = Vg + (size_t)kv2 * D + h * 128 + ch * 8;
    s16x8 a0 = *(const s16x8*)src;
    s16x8 a1 = *(const s16x8*)(src + D);
#pragma unroll
    for (int it = 0; it < 2; ++it) {
      int id = it * 512 + t;
      int kv = id >> 4, c0 = id & 15;
      gload_lds16(Kg + (size_t)kv * D + h * 128 + ((c0 ^ (kv & 7)) << 3), &Ks[0][id * 8]);
    }
#pragma unroll
    for (int jj = 0; jj < 8; ++jj) {
      int d = ch * 8 + jj;
      int sw = ((ch ^ jj) & 7) << 3;
      unsigned pr = (unsigned)(u16)a0[jj] | ((unsigned)(u16)a1[jj] << 16);
      *(unsigned*)&Vt[0][d * 64 + (kv2 ^ sw)] = pr;
    }
  }

  for (int kt = 0; kt < ntiles; ++kt) {
    const int b = kt & 1;
    const int kv0 = kt * 64;
    __syncthreads();

    s16x8 a0, a1;
    const bool pf = (kt + 1 < ntiles);
    if (pf) {
      const u16* src = Vg + (size_t)(kv0 + 64 + kv2) * D + h * 128 + ch * 8;
      a0 = *(const s16x8*)src;
      a1 = *(const s16x8*)(src + D);
#pragma unroll
      for (int it = 0; it < 2; ++it) {
        int id = it * 512 + t;
        int kv = id >> 4, c0 = id & 15;
        gload_lds16(Kg + (size_t)(kv0 + 64 + kv) * D + h * 128 + ((c0 ^ (kv & 7)) << 3),
                    &Ks[b ^ 1][id * 8]);
      }
    }

    if (kv0 <= qw0 + 15) {
      const bool masked = (kv0 + 63 > qw0);

      f32x4 st[4] = {};
      __builtin_amdgcn_s_setprio(1);
#pragma unroll
      for (int nt = 0; nt < 4; ++nt) {
        int kv = nt * 16 + lr;
        int sw = kv & 7;
#pragma unroll
        for (int kc = 0; kc < 4; ++kc) {
          s16x8 kf = *(const s16x8*)&Ks[b][kv * 128 + (((4 * kc + lk) ^ sw) << 3)];
          st[nt] = __builtin_amdgcn_mfma_f32_16x16x32_bf16(qf[kc], kf, st[nt], 0, 0, 0);
        }
      }
      __builtin_amdgcn_s_setprio(0);

      float pmax_[4];
#pragma unroll
      for (int r = 0; r < 4; ++r) {
        int q_r = qw0 + lk * 4 + r;
        if (masked) {
#pragma unroll
          for (int nt = 0; nt < 4; ++nt) {
            float sv = st[nt][r] * scale2;
            if (kv0 + nt * 16 + lr > q_r) sv = -1e30f;
            st[nt][r] = sv;
          }
        } else {
#pragma unroll
          for (int nt = 0; nt < 4; ++nt) st[nt][r] *= scale2;
        }
        float pm = fmaxf(fmaxf(st[0][r], st[1][r]), fmaxf(st[2][r], st[3][r]));
        pm = fmaxf(pm, __shfl_xor(pm, 1));
        pm = fmaxf(pm, __shfl_xor(pm, 2));
        pm = fmaxf(pm, __shfl_xor(pm, 4));
        pm = fmaxf(pm, __shfl_xor(pm, 8));
        pmax_[r] = pm;
      }
      bool nr = (pmax_[0] > m_r[0] + 8.f) || (pmax_[1] > m_r[1] + 8.f) ||
                (pmax_[2] > m_r[2] + 8.f) || (pmax_[3] > m_r[3] + 8.f);
      if (__any(nr)) {
#pragma unroll
        for (int r = 0; r < 4; ++r) {
          float mn = fmaxf(m_r[r], pmax_[r]);
          float al = __builtin_amdgcn_exp2f(m_r[r] - mn);
          m_r[r] = mn; l_r[r] *= al;
#pragma unroll
          for (int nb = 0; nb < 8; ++nb) o[nb][r] *= al;
        }
      }
#pragma unroll
      for (int r = 0; r < 4; ++r) {
        int ql = lk * 4 + r;
        int swp = ((ql >> 1) & 7) << 3;
        float ps = 0.f;
#pragma unroll
        for (int nt = 0; nt < 4; ++nt) {
          float pv = __builtin_amdgcn_exp2f(st[nt][r] - m_r[r]);
          ps += pv;
          Ps[wid][ql * 64 + ((nt * 16 + lr) ^ swp)] = f2bf(pv);
        }
        ps += __shfl_xor(ps, 1);
        ps += __shfl_xor(ps, 2);
        ps += __shfl_xor(ps, 4);
        ps += __shfl_xor(ps, 8);
        l_r[r] += ps;
      }
      asm volatile("s_waitcnt lgkmcnt(0)" ::: "memory");

      s16x8 pa[2];
#pragma unroll
      for (int ks = 0; ks < 2; ++ks) {
        int col = (ks * 32 + lk * 8) ^ (((lr >> 1) & 7) << 3);
        pa[ks] = *(const s16x8*)&Ps[wid][lr * 64 + col];
      }

      __builtin_amdgcn_s_setprio(1);
#pragma unroll
      for (int ks = 0; ks < 2; ++ks) {
#pragma unroll
        for (int nb = 0; nb < 8; ++nb) {
          int d = nb * 16 + lr;
          int g = (((d >> 3) ^ d) & 7) << 3;
          s16x8 vf = *(const s16x8*)&Vt[b][d * 64 + ((ks * 32 + lk * 8) ^ g)];
          o[nb] = __builtin_amdgcn_mfma_f32_16x16x32_bf16(pa[ks], vf, o[nb], 0, 0, 0);
        }
      }
      __builtin_amdgcn_s_setprio(0);
    }

    if (pf) {
#pragma unroll
      for (int jj = 0; jj < 8; ++jj) {
        int d = ch * 8 + jj;
        int sw = ((ch ^ jj) & 7) << 3;
        unsigned pr = (unsigned)(u16)a0[jj] | ((unsigned)(u16)a1[jj] << 16);
        *(unsigned*)&Vt[b ^ 1][d * 64 + (kv2 ^ sw)] = pr;
      }
    }
  }

#pragma unroll
  for (int r = 0; r < 4; ++r) {
    float inv = 1.f / l_r[r];
    int q_r = qw0 + lk * 4 + r;
#pragma unroll
    for (int nb = 0; nb < 8; ++nb)
      Ctx[(size_t)q_r * D + h * 128 + nb * 16 + lr] = f2bf(o[nb][r] * inv);
  }
}

// ---------------- launcher ----------------
extern "C" void kernel_launch(void* const* d_in, const int* in_sizes, int n_in,
                              void* d_out, int out_size, void* d_ws, size_t ws_size,
                              hipStream_t stream) {
  const int S = 2048, D = 4096, H = 32;
  const size_t SD = (size_t)S * D, DD = (size_t)D * D;

  const float* X  = (const float*)d_in[0];
  const float* Wq = (const float*)d_in[1];
  const float* Wk = (const float*)d_in[2];
  const float* Wv = (const float*)d_in[3];
  const float* Wo = (const float*)d_in[4];
  const float* bo = (const float*)d_in[5];
  const float* cs = (const float*)d_in[6];
  const float* sn = (const float*)d_in[7];

  u16* WB = (u16*)d_ws;
  u16* Xb = WB + DD;
  u16* Qb = Xb + SD;
  u16* Kb = Qb + SD;
  u16* Vb = Kb + SD;

  dim3 blk(256);
  dim3 g2(256);      // (2048/128) x (4096/256)
  dim3 b2(512);

  cvt_f32_bf16<<<(int)(SD / 1024), blk, 0, stream>>>(X, Xb, (int)SD);
  cvt_f32_bf16<<<(int)(DD / 1024), blk, 0, stream>>>(Wq, WB, (int)DD);
  gemm_bt2<u16, false><<<g2, b2, 0, stream>>>(Xb, WB, Qb, nullptr, S, D, D);
  cvt_f32_bf16<<<(int)(DD / 1024), blk, 0, stream>>>(Wk, WB, (int)DD);
  gemm_bt2<u16, false><<<g2, b2, 0, stream>>>(Xb, WB, Kb, nullptr, S, D, D);
  cvt_f32_bf16<<<(int)(DD / 1024), blk, 0, stream>>>(Wv, WB, (int)DD);
  gemm_bt2<u16, false><<<g2, b2, 0, stream>>>(Xb, WB, Vb, nullptr, S, D, D);

  rope_qk<<<(S * H * 64) / 256, blk, 0, stream>>>(Qb, Kb, cs, sn);

  flash_attn<<<dim3(512), dim3(512), 0, stream>>>(Qb, Kb, Vb, Xb /*Ctx*/);

  cvt_f32_bf16<<<(int)(DD / 1024), blk, 0, stream>>>(Wo, WB, (int)DD);
  gemm_bt2<float, true><<<g2, b2, 0, stream>>>(Xb, WB, (float*)d_out, bo, S, D, D);
}